// Round 8
// baseline (342.743 us; speedup 1.0000x reference)
//
#include <hip/hip_runtime.h>
#include <cstdint>
#include <cstddef>

// ---------------- workspace layout (bytes) ----------------
// Wp   : packed gate-interleaved weight, bf16, 768x1024 (4 cb x 32 kb tiles, 192x32) = 1,572,864
// Fp   : packed fco_w, bf16, 256x256 (2 nb x 8 kb tiles, 128x32)                     =   131,072
// bp   : permuted bias (c = h*3+g), f32, 768
// hvp  : packed hidden vector, bf16, 32768x256 (256 mb x 8 kb tiles, 128x32)
#define WS_WP   0
#define WS_FCO  1572864
#define WS_BP   1703936
#define WS_HVP  1707008

typedef __attribute__((ext_vector_type(8))) __bf16 bf16x8;
typedef __attribute__((ext_vector_type(4))) float floatx4;

__device__ __forceinline__ unsigned short f2bf(float f) {
  unsigned int u = __builtin_bit_cast(unsigned int, f);
  u += 0x7fffu + ((u >> 16) & 1u);   // RNE
  return (unsigned short)(u >> 16);
}

__device__ __forceinline__ float sigmf(float z) {
  return __builtin_amdgcn_rcpf(1.f + __expf(-z));
}
__device__ __forceinline__ float tanh_(float z) {
  return 1.f - 2.f * __builtin_amdgcn_rcpf(1.f + __expf(2.f * z));
}

__device__ __forceinline__ void gld16(const void* g, void* l) {
  __builtin_amdgcn_global_load_lds(
      (const __attribute__((address_space(1))) unsigned int*)g,
      (__attribute__((address_space(3))) unsigned int*)l, 16, 0, 0);
}

// ---------------- merged pack kernel (R2 original: weights + fco only) ----------------
__global__ __launch_bounds__(256) void pack_k(
    const float* __restrict__ wr, const float* __restrict__ wi,
    const float* __restrict__ wj, const float* __restrict__ wk,
    const float* __restrict__ bx, const float* __restrict__ fw,
    unsigned short* __restrict__ Wp, unsigned short* __restrict__ Fp,
    float* __restrict__ bp) {
  int t = threadIdx.x;
  if (blockIdx.x < 384) {
    int gpp = blockIdx.x >> 7;        // 0..2 -> gates {input,output,cell}
    int oct = blockIdx.x & 127;       // f-octet
    int gp = gpp + 1;                 // skip dead forget gate
    int h = t;                        // 0..255, lane-contiguous
    int hb = h >> 6, hr = h & 63;     // hb wave-uniform
    int f0 = oct << 3;
    int fb = f0 >> 8, fr0 = f0 & 255;
    const int   comp_t[4][4] = {{0,1,2,3},{1,0,3,2},{2,3,0,1},{3,2,1,0}};
    const float sign_t[4][4] = {{1.f,-1.f,-1.f,-1.f},{1.f,1.f,-1.f,1.f},
                                {1.f,1.f,1.f,-1.f},{1.f,-1.f,1.f,1.f}};
    const float* srcs[4] = {wr, wi, wj, wk};
    const float* s = srcs[comp_t[hb][fb]] + ((size_t)((gp << 8) + fr0)) * 64 + hr;
    float sg = sign_t[hb][fb];
    unsigned short v[8];
#pragma unroll
    for (int j = 0; j < 8; ++j) v[j] = f2bf(sg * s[(size_t)j * 64]);
    int c = h * 3 + gpp;
    int cb = c / 192, nl = c % 192;
    int kb = oct >> 2, q = oct & 3;
    int idx16 = (nl << 2) + (q ^ ((nl >> 1) & 3));
    uint4 val = make_uint4(
        (unsigned)v[0] | ((unsigned)v[1] << 16), (unsigned)v[2] | ((unsigned)v[3] << 16),
        (unsigned)v[4] | ((unsigned)v[5] << 16), (unsigned)v[6] | ((unsigned)v[7] << 16));
    *(uint4*)(Wp + (size_t)(cb * 32 + kb) * 6144 + idx16 * 8) = val;
    if (oct == 0) bp[c] = bx[(gp << 8) + h];
  } else {
    int oct = blockIdx.x - 384;       // k-octet 0..31
    int n = t;
    int k0 = oct << 3;
    unsigned short v[8];
#pragma unroll
    for (int j = 0; j < 8; ++j) v[j] = f2bf(fw[(size_t)(k0 + j) * 256 + n]);
    int nb = n >> 7, nl = n & 127, kb = oct >> 2, q = oct & 3;
    int idx16 = (nl << 2) + (q ^ ((nl >> 1) & 3));
    uint4 val = make_uint4(
        (unsigned)v[0] | ((unsigned)v[1] << 16), (unsigned)v[2] | ((unsigned)v[3] << 16),
        (unsigned)v[4] | ((unsigned)v[5] << 16), (unsigned)v[6] | ((unsigned)v[7] << 16));
    *(uint4*)(Fp + (size_t)((nb << 3) + kb) * 4096 + idx16 * 8) = val;
  }
}

// ---------------- GEMM1 (A-direct) + fused LSTM gates ----------------
// THEORY (R8): the only change that ever moved gemm1 was deleting the A staging
// chain (R6 xp: -26+ us), but its pre-pass tax (~35 us HBM) made totals worse.
// This kernel deletes the chain WITHOUT a pre-pass: A-fragments load straight
// from x to VGPRs (each lane's fragment = 8 contiguous fp32 of one row -> two
// dwordx4), cvt'd once per step; A never touches LDS. LDS carries only B
// (3 x 12 KB, counted-vmcnt, 2-step staging lead). A-loads are issued TWO steps
// ahead into alternating named reg sets (raA/raB); one s_waitcnt vmcnt(11) per
// step certifies both A(kt+1) regs and B(kt+1) LDS before the barrier
// (outstanding after wait = A(kt+2) 8 + B(kt+2) 3 = 11). Block's 16 KB/step
// x-slab is L1-resident; each 128-B row segment fully consumed across q/half.
__global__ __launch_bounds__(256, 2) void gemm1_k(
    const float* __restrict__ x, const unsigned short* __restrict__ Wp,
    const float* __restrict__ bp, unsigned short* __restrict__ hvp) {
  __shared__ char smem[36864];                  // 3 x 12 KB B buffers; epi 32x201 f32
  float* zep = (float*)smem;

  const int t = threadIdx.x;
  const int lane = t & 63, wid = t >> 6;
  const int wm = wid >> 1, wn = wid & 1;
  const int lrow = lane & 15, q = lane >> 4;
  const int rowt = blockIdx.x;                  // 0..255 (fast dim: W stays L2-hot)
  const int cby = blockIdx.y;                   // 0..3
  const float* xfrag = x + (size_t)(rowt * 128 + wm * 64 + lrow) * 1024 + q * 8;
  const unsigned short* wpb = Wp + (size_t)cby * 32 * 6144;

  floatx4 acc[4][6];
#pragma unroll
  for (int i = 0; i < 4; ++i)
#pragma unroll
    for (int j = 0; j < 6; ++j) acc[i][j] = (floatx4){0.f, 0.f, 0.f, 0.f};

  bf16x8 afc[4];                                // cvt'd A fragments for current step

#define STAGE_B(bufi, kt)                                                     \
  {                                                                           \
    unsigned short* sB_ = (unsigned short*)(smem + (bufi) * 12288);           \
    const unsigned short* bt_ = wpb + (size_t)(kt) * 6144;                    \
    _Pragma("unroll")                                                         \
    for (int i_ = 0; i_ < 3; ++i_) {                                          \
      int s_ = t + i_ * 256;                                                  \
      gld16(bt_ + s_ * 8, sB_ + s_ * 8);                                      \
    }                                                                         \
  }
#define LOAD_A(R, kt)                                                         \
  {                                                                           \
    const float* p_ = xfrag + (kt) * 32;                                      \
    _Pragma("unroll")                                                         \
    for (int mt_ = 0; mt_ < 4; ++mt_) {                                       \
      R[2 * mt_]     = *(const float4*)(p_ + mt_ * 16384);                    \
      R[2 * mt_ + 1] = *(const float4*)(p_ + mt_ * 16384 + 4);                \
    }                                                                         \
  }
#define CVT_A(R)                                                              \
  {                                                                           \
    _Pragma("unroll")                                                         \
    for (int mt_ = 0; mt_ < 4; ++mt_) {                                       \
      bf16x8 v_;                                                              \
      v_[0] = (__bf16)R[2 * mt_].x;     v_[1] = (__bf16)R[2 * mt_].y;         \
      v_[2] = (__bf16)R[2 * mt_].z;     v_[3] = (__bf16)R[2 * mt_].w;         \
      v_[4] = (__bf16)R[2 * mt_ + 1].x; v_[5] = (__bf16)R[2 * mt_ + 1].y;     \
      v_[6] = (__bf16)R[2 * mt_ + 1].z; v_[7] = (__bf16)R[2 * mt_ + 1].w;     \
      afc[mt_] = v_;                                                          \
    }                                                                         \
  }
#define COMPUTE(bufi)                                                         \
  {                                                                           \
    const unsigned short* sB_ = (const unsigned short*)(smem + (bufi) * 12288);\
    bf16x8 bf[6];                                                             \
    _Pragma("unroll")                                                         \
    for (int nt = 0; nt < 6; ++nt) {                                          \
      int n = wn * 96 + nt * 16 + lrow;                                       \
      int off16 = (n << 2) + (q ^ ((n >> 1) & 3));                            \
      bf[nt] = *(const bf16x8*)(const void*)(sB_ + off16 * 8);                \
    }                                                                         \
    _Pragma("unroll")                                                         \
    for (int mt = 0; mt < 4; ++mt)                                            \
      _Pragma("unroll")                                                       \
      for (int nt = 0; nt < 6; ++nt)                                          \
        acc[mt][nt] = __builtin_amdgcn_mfma_f32_16x16x32_bf16(                \
            afc[mt], bf[nt], acc[mt][nt], 0, 0, 0);                           \
  }
// BODY(kt): RC holds raw A(kt+1) (issued at kt-1); RN receives A(kt+2).
#define BODY(kt, RC, RN)                                                      \
  {                                                                           \
    if ((kt) <= 29) {                                                         \
      LOAD_A(RN, (kt) + 2)                                                    \
      STAGE_B(((kt) + 2) % 3, (kt) + 2)                                       \
    }                                                                         \
    COMPUTE((kt) % 3)                                                         \
    if ((kt) <= 29) {                                                         \
      asm volatile("s_waitcnt vmcnt(11)" ::: "memory");                       \
    } else if ((kt) == 30) {                                                  \
      asm volatile("s_waitcnt vmcnt(0)" ::: "memory");                        \
    }                                                                         \
    if ((kt) <= 30) { CVT_A(RC) }                                             \
    asm volatile("s_waitcnt lgkmcnt(0)" ::: "memory");                        \
    __builtin_amdgcn_s_barrier();                                             \
    asm volatile("" ::: "memory");                                            \
  }

  float4 raA[8], raB[8];
  // Prologue: raA=A(0), raB=A(1); B(0)->buf0, B(1)->buf1.
  LOAD_A(raA, 0)
  STAGE_B(0, 0)
  LOAD_A(raB, 1)
  STAGE_B(1, 1)
  asm volatile("s_waitcnt vmcnt(11)" ::: "memory");   // A(0)+B(0) done
  CVT_A(raA)                                          // afc = A(0)
  __builtin_amdgcn_s_barrier();
  asm volatile("" ::: "memory");

  for (int kt2 = 0; kt2 < 32; kt2 += 2) {
    BODY(kt2, raB, raA)                         // even kt: RC=raB holds A(kt+1)
    BODY(kt2 + 1, raA, raB)                     // odd kt: RC=raA holds A(kt+1)
  }
#undef BODY
#undef COMPUTE
#undef CVT_A
#undef LOAD_A
#undef STAGE_B
  __syncthreads();                              // all K-loop LDS reads done before zep reuse

  // Epilogue: 4 passes of 32 rows via LDS (pitch 201 f32), fused gates,
  // hv stored in gemm2's packed-swizzled tile layout.
  const float* bp0 = bp + cby * 192;
  const int er = t >> 3, oc = t & 7;
#pragma unroll
  for (int pass = 0; pass < 4; ++pass) {
    if (wm == (pass >> 1)) {
      int mtb = (pass & 1) * 2;
#pragma unroll
      for (int mi = 0; mi < 2; ++mi)
#pragma unroll
        for (int nt = 0; nt < 6; ++nt)
#pragma unroll
          for (int r = 0; r < 4; ++r)
            zep[(mi * 16 + q * 4 + r) * 201 + wn * 96 + nt * 16 + lrow] = acc[mtb + mi][nt][r];
    }
    __syncthreads();
    {
      int ml = pass * 32 + er;                  // local row 0..127
      unsigned short v[8];
#pragma unroll
      for (int j = 0; j < 8; ++j) {
        int hl = oc * 8 + j;                    // 0..63 local h
        float zi = zep[er * 201 + hl * 3 + 0] + bp0[hl * 3 + 0];
        float zo = zep[er * 201 + hl * 3 + 1] + bp0[hl * 3 + 1];
        float zc = zep[er * 201 + hl * 3 + 2] + bp0[hl * 3 + 2];
        float it = sigmf(zi);
        float ot = sigmf(zo);
        float cc = it * tanh_(zc);
        v[j] = f2bf(ot * tanh_(cc));
      }
      int ktile = cby * 2 + (oc >> 2), qq = oc & 3;
      int idx16 = (ml << 2) + (qq ^ ((ml >> 1) & 3));
      uint4 val = make_uint4(
          (unsigned)v[0] | ((unsigned)v[1] << 16), (unsigned)v[2] | ((unsigned)v[3] << 16),
          (unsigned)v[4] | ((unsigned)v[5] << 16), (unsigned)v[6] | ((unsigned)v[7] << 16));
      *(uint4*)(hvp + (size_t)(rowt * 8 + ktile) * 4096 + idx16 * 8) = val;
    }
    __syncthreads();
  }
}

// ---------------- GEMM2: out = hv @ fco_w + fco_b, with A-prefetch ----------------
__global__ __launch_bounds__(256, 4) void gemm2_k(
    const unsigned short* __restrict__ hvp, const unsigned short* __restrict__ Fp,
    const float* __restrict__ fcob, float* __restrict__ out) {
  __shared__ unsigned short sB[32768];          // 64 KB: 8 k-tiles of 128x32
  const int t = threadIdx.x;
  const int lane = t & 63, wid = t >> 6;
  const int wm = wid >> 1, wn = wid & 1;
  const int lrow = lane & 15, q = lane >> 4;
  const int mb = blockIdx.x, nb = blockIdx.y;

  const unsigned short* fpb = Fp + (size_t)nb * 32768;
#pragma unroll
  for (int i = 0; i < 16; ++i) gld16(fpb + (t + i * 256) * 8, sB + (t + i * 256) * 8);

  floatx4 acc[4][4];
#pragma unroll
  for (int i = 0; i < 4; ++i)
#pragma unroll
    for (int j = 0; j < 4; ++j) acc[i][j] = (floatx4){0.f, 0.f, 0.f, 0.f};

  int aoff[4];
#pragma unroll
  for (int mt = 0; mt < 4; ++mt) {
    int m = wm * 64 + mt * 16 + lrow;
    aoff[mt] = ((m << 2) + (q ^ ((m >> 1) & 3))) * 8;
  }
  // Preload A(0) while Fp staging is in flight.
  bf16x8 afc[4];
  {
    const unsigned short* at_ = hvp + (size_t)(mb * 8) * 4096;
#pragma unroll
    for (int mt = 0; mt < 4; ++mt)
      afc[mt] = *(const bf16x8*)(const void*)(at_ + aoff[mt]);
  }
  __syncthreads();

#pragma unroll
  for (int kt = 0; kt < 8; ++kt) {
    bf16x8 afn[4];
    if (kt < 7) {
      const unsigned short* at_ = hvp + (size_t)(mb * 8 + kt + 1) * 4096;
#pragma unroll
      for (int mt = 0; mt < 4; ++mt)
        afn[mt] = *(const bf16x8*)(const void*)(at_ + aoff[mt]);
    }
    bf16x8 bf[4];
#pragma unroll
    for (int nt = 0; nt < 4; ++nt) {
      int n = wn * 64 + nt * 16 + lrow;
      int o = (n << 2) + (q ^ ((n >> 1) & 3));
      bf[nt] = *(const bf16x8*)(const void*)(sB + kt * 4096 + o * 8);
    }
#pragma unroll
    for (int mt = 0; mt < 4; ++mt)
#pragma unroll
      for (int nt = 0; nt < 4; ++nt)
        acc[mt][nt] = __builtin_amdgcn_mfma_f32_16x16x32_bf16(afc[mt], bf[nt], acc[mt][nt], 0, 0, 0);
    if (kt < 7) {
#pragma unroll
      for (int mt = 0; mt < 4; ++mt) afc[mt] = afn[mt];
    }
  }
#pragma unroll
  for (int nt = 0; nt < 4; ++nt) {
    int colg = nb * 128 + wn * 64 + nt * 16 + lrow;
    float bias = fcob[colg];
#pragma unroll
    for (int mt = 0; mt < 4; ++mt) {
      int rowg = mb * 128 + wm * 64 + mt * 16 + q * 4;
#pragma unroll
      for (int r = 0; r < 4; ++r)
        out[(size_t)(rowg + r) * 256 + colg] = acc[mt][nt][r] + bias;
    }
  }
}

extern "C" void kernel_launch(void* const* d_in, const int* in_sizes, int n_in,
                              void* d_out, int out_size, void* d_ws, size_t ws_size,
                              hipStream_t stream) {
  const float* x  = (const float*)d_in[0];
  const float* wr = (const float*)d_in[1];
  const float* wi = (const float*)d_in[2];
  const float* wj = (const float*)d_in[3];
  const float* wk = (const float*)d_in[4];
  const float* bx = (const float*)d_in[5];
  // d_in[6..9] = uh_* are dead (h0 == 0)
  const float* fw = (const float*)d_in[10];
  const float* fb = (const float*)d_in[11];
  char* ws = (char*)d_ws;
  unsigned short* Wp  = (unsigned short*)(ws + WS_WP);
  unsigned short* Fp  = (unsigned short*)(ws + WS_FCO);
  float*          bp  = (float*)(ws + WS_BP);
  unsigned short* hvp = (unsigned short*)(ws + WS_HVP);
  float*          out = (float*)d_out;

  hipLaunchKernelGGL(pack_k,  dim3(416),    dim3(256), 0, stream, wr, wi, wj, wk, bx, fw, Wp, Fp, bp);
  hipLaunchKernelGGL(gemm1_k, dim3(256, 4), dim3(256), 0, stream, x, Wp, bp, hvp);
  hipLaunchKernelGGL(gemm2_k, dim3(256, 2), dim3(256), 0, stream, hvp, Fp, fb, out);
}

// Round 9
// 301.092 us; speedup vs baseline: 1.1383x; 1.1383x over previous
//
#include <hip/hip_runtime.h>
#include <cstdint>
#include <cstddef>

// ---------------- workspace layout (bytes) ----------------
// Wp   : packed gate-interleaved weight, bf16, 768x1024 (4 cb x 32 kb tiles, 192x32) = 1,572,864
// Fp   : packed fco_w, bf16, 256x256 (2 nb x 8 kb tiles, 128x32)                     =   131,072
// bp   : permuted bias (c = h*3+g), f32, 768
// hvp  : packed hidden vector, bf16, 32768x256 (256 mb x 8 kb tiles, 128x32)         = 16,777,216
// xp   : packed input, bf16, 32768x1024 (256 mb x 32 kb tiles, 128x32)               = 67,108,864
#define WS_WP   0
#define WS_FCO  1572864
#define WS_BP   1703936
#define WS_HVP  1707008
#define WS_XP   18484224
#define WS_NEED 85593088ull

typedef __attribute__((ext_vector_type(8))) __bf16 bf16x8;
typedef __attribute__((ext_vector_type(4))) __bf16 bf16x4;
typedef __attribute__((ext_vector_type(4))) float floatx4;

__device__ __forceinline__ unsigned short f2bf(float f) {
  unsigned int u = __builtin_bit_cast(unsigned int, f);
  u += 0x7fffu + ((u >> 16) & 1u);   // RNE
  return (unsigned short)(u >> 16);
}

__device__ __forceinline__ float sigmf(float z) {
  return __builtin_amdgcn_rcpf(1.f + __expf(-z));
}
__device__ __forceinline__ float tanh_(float z) {
  return 1.f - 2.f * __builtin_amdgcn_rcpf(1.f + __expf(2.f * z));
}

__device__ __forceinline__ void gld16(const void* g, void* l) {
  __builtin_amdgcn_global_load_lds(
      (const __attribute__((address_space(1))) unsigned int*)g,
      (__attribute__((address_space(3))) unsigned int*)l, 16, 0, 0);
}

// ---------------- merged pack kernel (R6: weights + fco + x-prepack) ----------------
__global__ __launch_bounds__(256) void pack_k(
    const float* __restrict__ wr, const float* __restrict__ wi,
    const float* __restrict__ wj, const float* __restrict__ wk,
    const float* __restrict__ bx, const float* __restrict__ fw,
    const float* __restrict__ x,
    unsigned short* __restrict__ Wp, unsigned short* __restrict__ Fp,
    float* __restrict__ bp, unsigned short* __restrict__ xp) {
  int t = threadIdx.x;
  if (blockIdx.x < 384) {
    int gpp = blockIdx.x >> 7;        // 0..2 -> gates {input,output,cell}
    int oct = blockIdx.x & 127;       // f-octet
    int gp = gpp + 1;                 // skip dead forget gate
    int h = t;                        // 0..255, lane-contiguous
    int hb = h >> 6, hr = h & 63;     // hb wave-uniform
    int f0 = oct << 3;
    int fb = f0 >> 8, fr0 = f0 & 255;
    const int   comp_t[4][4] = {{0,1,2,3},{1,0,3,2},{2,3,0,1},{3,2,1,0}};
    const float sign_t[4][4] = {{1.f,-1.f,-1.f,-1.f},{1.f,1.f,-1.f,1.f},
                                {1.f,1.f,1.f,-1.f},{1.f,-1.f,1.f,1.f}};
    const float* srcs[4] = {wr, wi, wj, wk};
    const float* s = srcs[comp_t[hb][fb]] + ((size_t)((gp << 8) + fr0)) * 64 + hr;
    float sg = sign_t[hb][fb];
    unsigned short v[8];
#pragma unroll
    for (int j = 0; j < 8; ++j) v[j] = f2bf(sg * s[(size_t)j * 64]);
    int c = h * 3 + gpp;
    int cb = c / 192, nl = c % 192;
    int kb = oct >> 2, q = oct & 3;
    int idx16 = (nl << 2) + (q ^ ((nl >> 1) & 3));
    uint4 val = make_uint4(
        (unsigned)v[0] | ((unsigned)v[1] << 16), (unsigned)v[2] | ((unsigned)v[3] << 16),
        (unsigned)v[4] | ((unsigned)v[5] << 16), (unsigned)v[6] | ((unsigned)v[7] << 16));
    *(uint4*)(Wp + (size_t)(cb * 32 + kb) * 6144 + idx16 * 8) = val;
    if (oct == 0) bp[c] = bx[(gp << 8) + h];
  } else if (blockIdx.x < 416) {
    int oct = blockIdx.x - 384;       // k-octet 0..31
    int n = t;
    int k0 = oct << 3;
    unsigned short v[8];
#pragma unroll
    for (int j = 0; j < 8; ++j) v[j] = f2bf(fw[(size_t)(k0 + j) * 256 + n]);
    int nb = n >> 7, nl = n & 127, kb = oct >> 2, q = oct & 3;
    int idx16 = (nl << 2) + (q ^ ((nl >> 1) & 3));
    uint4 val = make_uint4(
        (unsigned)v[0] | ((unsigned)v[1] << 16), (unsigned)v[2] | ((unsigned)v[3] << 16),
        (unsigned)v[4] | ((unsigned)v[5] << 16), (unsigned)v[6] | ((unsigned)v[7] << 16));
    *(uint4*)(Fp + (size_t)((nb << 3) + kb) * 4096 + idx16 * 8) = val;
  } else {
    // x pre-pack: block handles (mb, 4 consecutive k-tiles)
    int b = blockIdx.x - 416;         // 0..2047
    int mb = b >> 3, kb8 = b & 7;
    const float* xb = x + (size_t)mb * 128 * 1024 + kb8 * 128;
    unsigned short* xpb = xp + ((size_t)mb * 32 + (size_t)kb8 * 4) * 4096;
#pragma unroll
    for (int i = 0; i < 8; ++i) {
      int s = t + i * 256;            // 0..2047
      int tile = s >> 9, idx16 = s & 511;
      int ml = idx16 >> 2;
      int q = (idx16 & 3) ^ ((ml >> 1) & 3);   // inverse of the XOR swizzle
      const float* src = xb + (size_t)ml * 1024 + tile * 32 + q * 8;
      float4 a0 = *(const float4*)src;
      float4 a1 = *(const float4*)(src + 4);
      uint4 val = make_uint4(
          (unsigned)f2bf(a0.x) | ((unsigned)f2bf(a0.y) << 16),
          (unsigned)f2bf(a0.z) | ((unsigned)f2bf(a0.w) << 16),
          (unsigned)f2bf(a1.x) | ((unsigned)f2bf(a1.y) << 16),
          (unsigned)f2bf(a1.z) | ((unsigned)f2bf(a1.w) << 16));
      *(uint4*)(xpb + (size_t)tile * 4096 + idx16 * 8) = val;
    }
  }
}

// ---------------- GEMM1 (xp path, 2-phase T3+T4+T5) + fused LSTM gates ----------------
// THEORY (R9): gemm1_xp (R6, pure-gld16 staging, 1 barrier/step) = ~88 us, the
// best variant by 23+. The catalog's regime-gate: T3 phase-split gives +28-41%
// ONLY on pure-gld16 double-buffered structures (m196/m201) -- R4's phase-split
// failure was on the reg-staged kernel (WRITE_A chain inside the phases).
// gemm1_xp is the first faithful host. This kernel ports the m201 per-phase
// pattern: each K-step = 2 phases of 12 MFMAs,
//   {ds_reads; stage-issue | counted-vmcnt; s_barrier; lgkmcnt(0);
//    sched_barrier; setprio(1); 12 MFMA; setprio(0); s_barrier}
// vmcnt never 0 in the main loop (only the tail). 3-buffer rotation unchanged;
// stage(kt+2) issue is barrier-ordered after all reads of its target buffer.
__global__ __launch_bounds__(256, 2) void gemm1_xp_k(
    const unsigned short* __restrict__ xp, const unsigned short* __restrict__ Wp,
    const float* __restrict__ bp, unsigned short* __restrict__ hvp) {
  __shared__ char smem[61440];                  // 3 x 20 KB (A bf16 8K + B bf16 12K)
  float* zep = (float*)smem;                    // epilogue: 32 x 201 f32 = 25.7 KB

  const int t = threadIdx.x;
  const int lane = t & 63, wid = t >> 6;
  const int wm = wid >> 1, wn = wid & 1;
  const int lrow = lane & 15, q = lane >> 4;
  const int rowt = blockIdx.x;                  // 0..255 (128-row tile; fast dim)
  const int cby = blockIdx.y;                   // 0..3
  const unsigned short* apb = xp + (size_t)rowt * 32 * 4096;
  const unsigned short* wpb = Wp + (size_t)cby * 32 * 6144;

  floatx4 acc[4][6];
#pragma unroll
  for (int i = 0; i < 4; ++i)
#pragma unroll
    for (int j = 0; j < 6; ++j) acc[i][j] = (floatx4){0.f, 0.f, 0.f, 0.f};

  // 5 gld16/thread/step: A 512 slots (2), B 768 slots (3). All linear.
#define STAGE(bufi, kt)                                                       \
  {                                                                           \
    char* base_ = smem + (bufi) * 20480;                                      \
    unsigned short* sA_ = (unsigned short*)base_;                             \
    unsigned short* sB_ = (unsigned short*)(base_ + 8192);                    \
    const unsigned short* at_ = apb + (size_t)(kt) * 4096;                    \
    const unsigned short* bt_ = wpb + (size_t)(kt) * 6144;                    \
    gld16(at_ + t * 8, sA_ + t * 8);                                          \
    gld16(at_ + (t + 256) * 8, sA_ + (t + 256) * 8);                          \
    _Pragma("unroll")                                                         \
    for (int i_ = 0; i_ < 3; ++i_) {                                          \
      int s_ = t + i_ * 256;                                                  \
      gld16(bt_ + s_ * 8, sB_ + s_ * 8);                                      \
    }                                                                         \
  }

  // Prologue: buffers 0 and 1 in flight; wait buffer 0 (5 newest outstanding).
  STAGE(0, 0)
  STAGE(1, 1)
  asm volatile("s_waitcnt vmcnt(5)" ::: "memory");
  __builtin_amdgcn_s_barrier();
  asm volatile("" ::: "memory");

  // Invariant at top of iter kt: buf[kt%3] published; stage(kt+1) in flight.
  for (int kt = 0; kt < 32; ++kt) {
    const unsigned short* sA_ = (const unsigned short*)(smem + (kt % 3) * 20480);
    const unsigned short* sB_ = sA_ + 4096;
    bf16x8 af[4], bf[6];
    // ---- Phase 1: A reads + first B half + stage issue ----
#pragma unroll
    for (int mt = 0; mt < 4; ++mt) {
      int m = wm * 64 + mt * 16 + lrow;
      int slot = (m << 2) + (q ^ ((m >> 1) & 3));
      af[mt] = *(const bf16x8*)(const void*)(sA_ + slot * 8);
    }
#pragma unroll
    for (int nt = 0; nt < 3; ++nt) {
      int n = wn * 96 + nt * 16 + lrow;
      int off16 = (n << 2) + (q ^ ((n >> 1) & 3));
      bf[nt] = *(const bf16x8*)(const void*)(sB_ + off16 * 8);
    }
    if (kt < 30) STAGE((kt + 2) % 3, kt + 2)
    __builtin_amdgcn_s_barrier();
    asm volatile("s_waitcnt lgkmcnt(0)" ::: "memory");
    __builtin_amdgcn_sched_barrier(0);
    __builtin_amdgcn_s_setprio(1);
#pragma unroll
    for (int mt = 0; mt < 4; ++mt)
#pragma unroll
      for (int nt = 0; nt < 3; ++nt)
        acc[mt][nt] = __builtin_amdgcn_mfma_f32_16x16x32_bf16(
            af[mt], bf[nt], acc[mt][nt], 0, 0, 0);
    __builtin_amdgcn_s_setprio(0);
    __builtin_amdgcn_sched_barrier(0);
    __builtin_amdgcn_s_barrier();
    // ---- Phase 2: second B half + counted vmcnt (certify kt+1) ----
#pragma unroll
    for (int nt = 3; nt < 6; ++nt) {
      int n = wn * 96 + nt * 16 + lrow;
      int off16 = (n << 2) + (q ^ ((n >> 1) & 3));
      bf[nt] = *(const bf16x8*)(const void*)(sB_ + off16 * 8);
    }
    if (kt < 30) {
      asm volatile("s_waitcnt vmcnt(5)" ::: "memory");   // kt+1 landed
    } else {
      asm volatile("s_waitcnt vmcnt(0)" ::: "memory");
    }
    __builtin_amdgcn_s_barrier();
    asm volatile("s_waitcnt lgkmcnt(0)" ::: "memory");
    __builtin_amdgcn_sched_barrier(0);
    __builtin_amdgcn_s_setprio(1);
#pragma unroll
    for (int mt = 0; mt < 4; ++mt)
#pragma unroll
      for (int nt = 3; nt < 6; ++nt)
        acc[mt][nt] = __builtin_amdgcn_mfma_f32_16x16x32_bf16(
            af[mt], bf[nt], acc[mt][nt], 0, 0, 0);
    __builtin_amdgcn_s_setprio(0);
    __builtin_amdgcn_sched_barrier(0);
    __builtin_amdgcn_s_barrier();
  }
#undef STAGE
  __syncthreads();                              // LDS reuse for epilogue

  // Epilogue: 4 passes of 32 rows via LDS (pitch 201 f32), fused gates,
  // hv stored in gemm2's packed-swizzled tile layout.
  const float* bp0 = bp + cby * 192;
  const int er = t >> 3, oc = t & 7;
#pragma unroll
  for (int pass = 0; pass < 4; ++pass) {
    if (wm == (pass >> 1)) {
      int mtb = (pass & 1) * 2;
#pragma unroll
      for (int mi = 0; mi < 2; ++mi)
#pragma unroll
        for (int nt = 0; nt < 6; ++nt)
#pragma unroll
          for (int r = 0; r < 4; ++r)
            zep[(mi * 16 + q * 4 + r) * 201 + wn * 96 + nt * 16 + lrow] = acc[mtb + mi][nt][r];
    }
    __syncthreads();
    {
      int ml = pass * 32 + er;                  // local row 0..127
      unsigned short v[8];
#pragma unroll
      for (int j = 0; j < 8; ++j) {
        int hl = oc * 8 + j;                    // 0..63 local h
        float zi = zep[er * 201 + hl * 3 + 0] + bp0[hl * 3 + 0];
        float zo = zep[er * 201 + hl * 3 + 1] + bp0[hl * 3 + 1];
        float zc = zep[er * 201 + hl * 3 + 2] + bp0[hl * 3 + 2];
        float it = sigmf(zi);
        float ot = sigmf(zo);
        float cc = it * tanh_(zc);
        v[j] = f2bf(ot * tanh_(cc));
      }
      int ktile = cby * 2 + (oc >> 2), qq = oc & 3;
      int idx16 = (ml << 2) + (qq ^ ((ml >> 1) & 3));
      uint4 val = make_uint4(
          (unsigned)v[0] | ((unsigned)v[1] << 16), (unsigned)v[2] | ((unsigned)v[3] << 16),
          (unsigned)v[4] | ((unsigned)v[5] << 16), (unsigned)v[6] | ((unsigned)v[7] << 16));
      *(uint4*)(hvp + (size_t)(rowt * 8 + ktile) * 4096 + idx16 * 8) = val;
    }
    __syncthreads();
  }
}

// ---------------- GEMM1 fallback (R2-style reg-staged, used when ws too small) ----------------
__global__ __launch_bounds__(512, 4) void gemm1_fb_k(
    const float* __restrict__ x, const unsigned short* __restrict__ Wp,
    const float* __restrict__ bp, unsigned short* __restrict__ hvp) {
  __shared__ char smem[57344];
  float* zep = (float*)smem;

  const int t = threadIdx.x;
  const int lane = t & 63, wid = t >> 6;
  const int wm = wid >> 2, wn = wid & 3;
  const int lrow = lane & 15, q = lane >> 4;
  const int rowt = blockIdx.x;
  const int nbq = blockIdx.y;
  const int cb0 = nbq * 2;
  const int row0 = rowt * 64;
  const float* xbase = x + (size_t)row0 * 1024;

  const int sr = t >> 3, kq = t & 7;
  const int sq8 = kq >> 1, shalf = kq & 1;

  floatx4 acc[2][6];
#pragma unroll
  for (int i = 0; i < 2; ++i)
#pragma unroll
    for (int j = 0; j < 6; ++j) acc[i][j] = (floatx4){0.f, 0.f, 0.f, 0.f};

#define STAGE_B(bufi, kt)                                                     \
  {                                                                           \
    unsigned short* sBs_ = (unsigned short*)(smem + (bufi) * 28672 + 4096);   \
    const unsigned short* bt0_ = Wp + ((size_t)cb0 * 32 + (kt)) * 6144;       \
    _Pragma("unroll")                                                         \
    for (int i_ = 0; i_ < 3; ++i_) {                                          \
      int s_ = t + i_ * 512;                                                  \
      int cbL_ = s_ >= 768;                                                   \
      const unsigned short* src_ =                                            \
          bt0_ + (size_t)cbL_ * 196608 + (s_ - cbL_ * 768) * 8;               \
      gld16(src_, sBs_ + s_ * 8);                                             \
    }                                                                         \
  }
#define LOAD_A(ra, kt)                                                        \
  { ra = *(const float4*)(xbase + (size_t)sr * 1024 + (kt) * 32 + kq * 4); }
#define WRITE_A(ra, bufi)                                                     \
  {                                                                           \
    unsigned short* sAs_ = (unsigned short*)(smem + (bufi) * 28672);          \
    int slot_ = (sr << 2) + (sq8 ^ ((sr >> 1) & 3));                          \
    bf16x4 v_;                                                                \
    v_[0] = (__bf16)ra.x; v_[1] = (__bf16)ra.y;                               \
    v_[2] = (__bf16)ra.z; v_[3] = (__bf16)ra.w;                               \
    *(bf16x4*)(sAs_ + slot_ * 8 + shalf * 4) = v_;                            \
  }
#define COMPUTE(bufi)                                                         \
  {                                                                           \
    const unsigned short* sA_ = (const unsigned short*)(smem + (bufi) * 28672);\
    const unsigned short* sB_ = sA_ + 2048;                                   \
    bf16x8 af[2], bf[6];                                                      \
    _Pragma("unroll")                                                         \
    for (int mt = 0; mt < 2; ++mt) {                                          \
      int m = wm * 32 + mt * 16 + lrow;                                       \
      int slot = (m << 2) + (q ^ ((m >> 1) & 3));                             \
      af[mt] = *(const bf16x8*)(const void*)(sA_ + slot * 8);                 \
    }                                                                         \
    _Pragma("unroll")                                                         \
    for (int nt = 0; nt < 6; ++nt) {                                          \
      int nl = (wn & 1) * 96 + nt * 16 + lrow;                                \
      int off16 = (nl << 2) + (q ^ ((nl >> 1) & 3));                          \
      bf[nt] = *(const bf16x8*)(const void*)(                                 \
          sB_ + ((size_t)(wn >> 1) * 768 + off16) * 8);                       \
    }                                                                         \
    _Pragma("unroll")                                                         \
    for (int mt = 0; mt < 2; ++mt)                                            \
      _Pragma("unroll")                                                       \
      for (int nt = 0; nt < 6; ++nt)                                          \
        acc[mt][nt] = __builtin_amdgcn_mfma_f32_16x16x32_bf16(                \
            af[mt], bf[nt], acc[mt][nt], 0, 0, 0);                            \
  }

  float4 ra;
  LOAD_A(ra, 0)
  STAGE_B(0, 0)
  WRITE_A(ra, 0)
  __syncthreads();

  for (int kt = 0; kt < 32; ++kt) {
    if (kt < 31) {
      LOAD_A(ra, kt + 1)
      STAGE_B((kt + 1) & 1, kt + 1)
    }
    COMPUTE(kt & 1)
    if (kt < 31) WRITE_A(ra, (kt + 1) & 1)
    __syncthreads();
  }
#undef COMPUTE
#undef STAGE_B
#undef LOAD_A
#undef WRITE_A

  const float* bp0 = bp + cb0 * 192;
  const int er = t >> 4, oc = t & 15;
  const int cbL = oc >> 3, oo = oc & 7;
  const int mb128 = rowt >> 1;
#pragma unroll
  for (int pass = 0; pass < 2; ++pass) {
    if (wm == pass) {
#pragma unroll
      for (int mt = 0; mt < 2; ++mt)
#pragma unroll
        for (int nt = 0; nt < 6; ++nt)
#pragma unroll
          for (int r = 0; r < 4; ++r)
            zep[(mt * 16 + q * 4 + r) * 385 + wn * 96 + nt * 16 + lrow] = acc[mt][nt][r];
    }
    __syncthreads();
    {
      int ml = (rowt & 1) * 64 + pass * 32 + er;
      unsigned short v[8];
#pragma unroll
      for (int j = 0; j < 8; ++j) {
        int hl = oo * 8 + j;
        int cz = cbL * 192 + hl * 3;
        float zi = zep[er * 385 + cz + 0] + bp0[cz + 0];
        float zo = zep[er * 385 + cz + 1] + bp0[cz + 1];
        float zc = zep[er * 385 + cz + 2] + bp0[cz + 2];
        float it = sigmf(zi);
        float ot = sigmf(zo);
        float cc = it * tanh_(zc);
        v[j] = f2bf(ot * tanh_(cc));
      }
      int ktile = (cb0 + cbL) * 2 + (oo >> 2), qq = oo & 3;
      int idx16 = (ml << 2) + (qq ^ ((ml >> 1) & 3));
      uint4 val = make_uint4(
          (unsigned)v[0] | ((unsigned)v[1] << 16), (unsigned)v[2] | ((unsigned)v[3] << 16),
          (unsigned)v[4] | ((unsigned)v[5] << 16), (unsigned)v[6] | ((unsigned)v[7] << 16));
      *(uint4*)(hvp + (size_t)(mb128 * 8 + ktile) * 4096 + idx16 * 8) = val;
    }
    __syncthreads();
  }
}

// ---------------- GEMM2: out = hv @ fco_w + fco_b, with A-prefetch ----------------
__global__ __launch_bounds__(256, 4) void gemm2_k(
    const unsigned short* __restrict__ hvp, const unsigned short* __restrict__ Fp,
    const float* __restrict__ fcob, float* __restrict__ out) {
  __shared__ unsigned short sB[32768];          // 64 KB: 8 k-tiles of 128x32
  const int t = threadIdx.x;
  const int lane = t & 63, wid = t >> 6;
  const int wm = wid >> 1, wn = wid & 1;
  const int lrow = lane & 15, q = lane >> 4;
  const int mb = blockIdx.x, nb = blockIdx.y;

  const unsigned short* fpb = Fp + (size_t)nb * 32768;
#pragma unroll
  for (int i = 0; i < 16; ++i) gld16(fpb + (t + i * 256) * 8, sB + (t + i * 256) * 8);

  floatx4 acc[4][4];
#pragma unroll
  for (int i = 0; i < 4; ++i)
#pragma unroll
    for (int j = 0; j < 4; ++j) acc[i][j] = (floatx4){0.f, 0.f, 0.f, 0.f};

  int aoff[4];
#pragma unroll
  for (int mt = 0; mt < 4; ++mt) {
    int m = wm * 64 + mt * 16 + lrow;
    aoff[mt] = ((m << 2) + (q ^ ((m >> 1) & 3))) * 8;
  }
  // Preload A(0) while Fp staging is in flight.
  bf16x8 afc[4];
  {
    const unsigned short* at_ = hvp + (size_t)(mb * 8) * 4096;
#pragma unroll
    for (int mt = 0; mt < 4; ++mt)
      afc[mt] = *(const bf16x8*)(const void*)(at_ + aoff[mt]);
  }
  __syncthreads();

#pragma unroll
  for (int kt = 0; kt < 8; ++kt) {
    bf16x8 afn[4];
    if (kt < 7) {
      const unsigned short* at_ = hvp + (size_t)(mb * 8 + kt + 1) * 4096;
#pragma unroll
      for (int mt = 0; mt < 4; ++mt)
        afn[mt] = *(const bf16x8*)(const void*)(at_ + aoff[mt]);
    }
    bf16x8 bf[4];
#pragma unroll
    for (int nt = 0; nt < 4; ++nt) {
      int n = wn * 64 + nt * 16 + lrow;
      int o = (n << 2) + (q ^ ((n >> 1) & 3));
      bf[nt] = *(const bf16x8*)(const void*)(sB + kt * 4096 + o * 8);
    }
#pragma unroll
    for (int mt = 0; mt < 4; ++mt)
#pragma unroll
      for (int nt = 0; nt < 4; ++nt)
        acc[mt][nt] = __builtin_amdgcn_mfma_f32_16x16x32_bf16(afc[mt], bf[nt], acc[mt][nt], 0, 0, 0);
    if (kt < 7) {
#pragma unroll
      for (int mt = 0; mt < 4; ++mt) afc[mt] = afn[mt];
    }
  }
#pragma unroll
  for (int nt = 0; nt < 4; ++nt) {
    int colg = nb * 128 + wn * 64 + nt * 16 + lrow;
    float bias = fcob[colg];
#pragma unroll
    for (int mt = 0; mt < 4; ++mt) {
      int rowg = mb * 128 + wm * 64 + mt * 16 + q * 4;
#pragma unroll
      for (int r = 0; r < 4; ++r)
        out[(size_t)(rowg + r) * 256 + colg] = acc[mt][nt][r] + bias;
    }
  }
}

extern "C" void kernel_launch(void* const* d_in, const int* in_sizes, int n_in,
                              void* d_out, int out_size, void* d_ws, size_t ws_size,
                              hipStream_t stream) {
  const float* x  = (const float*)d_in[0];
  const float* wr = (const float*)d_in[1];
  const float* wi = (const float*)d_in[2];
  const float* wj = (const float*)d_in[3];
  const float* wk = (const float*)d_in[4];
  const float* bx = (const float*)d_in[5];
  // d_in[6..9] = uh_* are dead (h0 == 0)
  const float* fw = (const float*)d_in[10];
  const float* fb = (const float*)d_in[11];
  char* ws = (char*)d_ws;
  unsigned short* Wp  = (unsigned short*)(ws + WS_WP);
  unsigned short* Fp  = (unsigned short*)(ws + WS_FCO);
  float*          bp  = (float*)(ws + WS_BP);
  unsigned short* hvp = (unsigned short*)(ws + WS_HVP);
  float*          out = (float*)d_out;

  const bool big = ws_size >= WS_NEED;
  unsigned short* xp = big ? (unsigned short*)(ws + WS_XP) : hvp;  // dummy if !big

  hipLaunchKernelGGL(pack_k, dim3(big ? 2464 : 416), dim3(256), 0, stream,
                     wr, wi, wj, wk, bx, fw, x, Wp, Fp, bp, xp);
  if (big) {
    hipLaunchKernelGGL(gemm1_xp_k, dim3(256, 4), dim3(256), 0, stream, xp, Wp, bp, hvp);
  } else {
    hipLaunchKernelGGL(gemm1_fb_k, dim3(512, 2), dim3(512), 0, stream, x, Wp, bp, hvp);
  }
  hipLaunchKernelGGL(gemm2_k, dim3(256, 2), dim3(256), 0, stream, hvp, Fp, fb, out);
}

// Round 10
// 288.531 us; speedup vs baseline: 1.1879x; 1.0435x over previous
//
#include <hip/hip_runtime.h>
#include <cstdint>
#include <cstddef>

// ---------------- workspace layout (bytes) ----------------
// Wp   : packed gate-interleaved weight, bf16, 768x1024 (4 cb x 32 kb tiles, 192x32) = 1,572,864
// Fp   : packed fco_w, bf16, 256x256 (2 nb x 8 kb tiles, 128x32)                     =   131,072
// bp   : permuted bias (c = h*3+g), f32, 768
// hvp  : packed hidden vector, bf16, 32768x256 (256 mb x 8 kb tiles, 128x32)
#define WS_WP   0
#define WS_FCO  1572864
#define WS_BP   1703936
#define WS_HVP  1707008

typedef __attribute__((ext_vector_type(8))) __bf16 bf16x8;
typedef __attribute__((ext_vector_type(4))) __bf16 bf16x4;
typedef __attribute__((ext_vector_type(4))) float floatx4;

__device__ __forceinline__ unsigned short f2bf(float f) {
  unsigned int u = __builtin_bit_cast(unsigned int, f);
  u += 0x7fffu + ((u >> 16) & 1u);   // RNE
  return (unsigned short)(u >> 16);
}

__device__ __forceinline__ float sigmf(float z) {
  return __builtin_amdgcn_rcpf(1.f + __expf(-z));
}
__device__ __forceinline__ float tanh_(float z) {
  return 1.f - 2.f * __builtin_amdgcn_rcpf(1.f + __expf(2.f * z));
}

__device__ __forceinline__ void gld16(const void* g, void* l) {
  __builtin_amdgcn_global_load_lds(
      (const __attribute__((address_space(1))) unsigned int*)g,
      (__attribute__((address_space(3))) unsigned int*)l, 16, 0, 0);
}

// ---------------- merged pack kernel ----------------
__global__ __launch_bounds__(256) void pack_k(
    const float* __restrict__ wr, const float* __restrict__ wi,
    const float* __restrict__ wj, const float* __restrict__ wk,
    const float* __restrict__ bx, const float* __restrict__ fw,
    unsigned short* __restrict__ Wp, unsigned short* __restrict__ Fp,
    float* __restrict__ bp) {
  int t = threadIdx.x;
  if (blockIdx.x < 384) {
    int gpp = blockIdx.x >> 7;        // 0..2 -> gates {input,output,cell}
    int oct = blockIdx.x & 127;       // f-octet
    int gp = gpp + 1;                 // skip dead forget gate
    int h = t;                        // 0..255, lane-contiguous
    int hb = h >> 6, hr = h & 63;     // hb wave-uniform
    int f0 = oct << 3;
    int fb = f0 >> 8, fr0 = f0 & 255;
    const int   comp_t[4][4] = {{0,1,2,3},{1,0,3,2},{2,3,0,1},{3,2,1,0}};
    const float sign_t[4][4] = {{1.f,-1.f,-1.f,-1.f},{1.f,1.f,-1.f,1.f},
                                {1.f,1.f,1.f,-1.f},{1.f,-1.f,1.f,1.f}};
    const float* srcs[4] = {wr, wi, wj, wk};
    const float* s = srcs[comp_t[hb][fb]] + ((size_t)((gp << 8) + fr0)) * 64 + hr;
    float sg = sign_t[hb][fb];
    unsigned short v[8];
#pragma unroll
    for (int j = 0; j < 8; ++j) v[j] = f2bf(sg * s[(size_t)j * 64]);
    int c = h * 3 + gpp;
    int cb = c / 192, nl = c % 192;
    int kb = oct >> 2, q = oct & 3;
    int idx16 = (nl << 2) + (q ^ ((nl >> 1) & 3));
    uint4 val = make_uint4(
        (unsigned)v[0] | ((unsigned)v[1] << 16), (unsigned)v[2] | ((unsigned)v[3] << 16),
        (unsigned)v[4] | ((unsigned)v[5] << 16), (unsigned)v[6] | ((unsigned)v[7] << 16));
    *(uint4*)(Wp + (size_t)(cb * 32 + kb) * 6144 + idx16 * 8) = val;
    if (oct == 0) bp[c] = bx[(gp << 8) + h];
  } else {
    int oct = blockIdx.x - 384;       // k-octet 0..31
    int n = t;
    int k0 = oct << 3;
    unsigned short v[8];
#pragma unroll
    for (int j = 0; j < 8; ++j) v[j] = f2bf(fw[(size_t)(k0 + j) * 256 + n]);
    int nb = n >> 7, nl = n & 127, kb = oct >> 2, q = oct & 3;
    int idx16 = (nl << 2) + (q ^ ((nl >> 1) & 3));
    uint4 val = make_uint4(
        (unsigned)v[0] | ((unsigned)v[1] << 16), (unsigned)v[2] | ((unsigned)v[3] << 16),
        (unsigned)v[4] | ((unsigned)v[5] << 16), (unsigned)v[6] | ((unsigned)v[7] << 16));
    *(uint4*)(Fp + (size_t)((nb << 3) + kb) * 4096 + idx16 * 8) = val;
  }
}

// ---------------- GEMM1 + fused LSTM gates ----------------
// R2 configuration (best measured: 287.0 us total, gemm1 ~111 us), restored
// verbatim. Tile 128x192, 4 waves of 64x96, BK=32, acc[4][6]. TRIPLE-buffered
// LDS (3 x 20 KB: A bf16 8K + B bf16 12K), staging issued 2 iterations ahead,
// raw s_barrier + counted s_waitcnt vmcnt(7) -- never drained to 0 in the main
// loop. Invariant at top of iter kt: buf[kt%3] fully staged; 7 vmem in flight
// for kt+1 (4 A float4 reg-loads + 3 B gld_lds). Six structural axes beyond
// this (LDS-traffic cut, x-read cut, phase-split, setprio, occupancy 2x,
// A-path removal x3) measured null or negative on this problem shape.
__global__ __launch_bounds__(256, 2) void gemm1_k(
    const float* __restrict__ x, const unsigned short* __restrict__ Wp,
    const float* __restrict__ bp, unsigned short* __restrict__ hvp) {
  __shared__ char smem[61440];                  // 3 x 20 KB; epilogue reuses 25.7 KB
  float* zep = (float*)smem;

  const int t = threadIdx.x;
  const int lane = t & 63, wid = t >> 6;
  const int wm = wid >> 1, wn = wid & 1;
  const int lrow = lane & 15, q = lane >> 4;
  const int rowt = blockIdx.x;                  // 0..255 (fast dim: W stays L2-hot)
  const int cby = blockIdx.y;                   // 0..3, 192 interleaved cols (64 h)
  const int row0 = rowt * 128;
  const float* xbase = x + (size_t)row0 * 1024;
  const unsigned short* wpb = Wp + (size_t)cby * 32 * 6144;

  // A staging mapping: thread t handles, for i in 0..3, the float4 at
  // row (i*32 + (t>>3)), k-quad (t&7). Per instr each 8-lane group covers one
  // 128B row segment (perfect coalescing).
  const int sr = t >> 3, skq = t & 7;
  const int sq8 = skq >> 1, shalf = skq & 1;

  floatx4 acc[4][6];
#pragma unroll
  for (int i = 0; i < 4; ++i)
#pragma unroll
    for (int j = 0; j < 6; ++j) acc[i][j] = (floatx4){0.f, 0.f, 0.f, 0.f};

#define STAGE_B(bufi, kt)                                                     \
  {                                                                           \
    unsigned short* sBs_ = (unsigned short*)(smem + (bufi) * 20480 + 8192);   \
    const unsigned short* bt_ = wpb + (size_t)(kt) * 6144;                    \
    _Pragma("unroll")                                                         \
    for (int i_ = 0; i_ < 3; ++i_) {                                          \
      int s_ = t + i_ * 256;                                                  \
      gld16(bt_ + s_ * 8, sBs_ + s_ * 8);                                     \
    }                                                                         \
  }
#define LOAD_A(ra, kt)                                                        \
  {                                                                           \
    const float* ab_ = xbase + (kt) * 32 + skq * 4;                           \
    _Pragma("unroll")                                                         \
    for (int i_ = 0; i_ < 4; ++i_)                                            \
      ra[i_] = *(const float4*)(ab_ + (size_t)(i_ * 32 + sr) * 1024);         \
  }
#define WRITE_A(ra, bufi)                                                     \
  {                                                                           \
    unsigned short* sAs_ = (unsigned short*)(smem + (bufi) * 20480);          \
    _Pragma("unroll")                                                         \
    for (int i_ = 0; i_ < 4; ++i_) {                                          \
      int m_ = i_ * 32 + sr;                                                  \
      int slot_ = (m_ << 2) + (sq8 ^ ((m_ >> 1) & 3));                        \
      bf16x4 v_;                                                              \
      v_[0] = (__bf16)ra[i_].x; v_[1] = (__bf16)ra[i_].y;                     \
      v_[2] = (__bf16)ra[i_].z; v_[3] = (__bf16)ra[i_].w;                     \
      *(bf16x4*)(sAs_ + slot_ * 8 + shalf * 4) = v_;                          \
    }                                                                         \
  }
#define COMPUTE(bufi)                                                         \
  {                                                                           \
    const unsigned short* sA_ = (const unsigned short*)(smem + (bufi) * 20480);\
    const unsigned short* sB_ = sA_ + 4096;                                   \
    bf16x8 af[4], bf[6];                                                      \
    _Pragma("unroll")                                                         \
    for (int mt = 0; mt < 4; ++mt) {                                          \
      int m = wm * 64 + mt * 16 + lrow;                                       \
      int slot = (m << 2) + (q ^ ((m >> 1) & 3));                             \
      af[mt] = *(const bf16x8*)(const void*)(sA_ + slot * 8);                 \
    }                                                                         \
    _Pragma("unroll")                                                         \
    for (int nt = 0; nt < 6; ++nt) {                                          \
      int n = wn * 96 + nt * 16 + lrow;                                       \
      int off16 = (n << 2) + (q ^ ((n >> 1) & 3));                            \
      bf[nt] = *(const bf16x8*)(const void*)(sB_ + off16 * 8);                \
    }                                                                         \
    _Pragma("unroll")                                                         \
    for (int mt = 0; mt < 4; ++mt)                                            \
      _Pragma("unroll")                                                       \
      for (int nt = 0; nt < 6; ++nt)                                          \
        acc[mt][nt] = __builtin_amdgcn_mfma_f32_16x16x32_bf16(                \
            af[mt], bf[nt], acc[mt][nt], 0, 0, 0);                            \
  }
// BODY: RC holds A(kt+1) (loads in flight or arrived); RN receives A(kt+2).
#define BODY(kt, RC, RN)                                                      \
  {                                                                           \
    if ((kt) < 30) {                                                          \
      LOAD_A(RN, (kt) + 2)                                                    \
      STAGE_B(((kt) + 2) % 3, (kt) + 2)                                       \
    }                                                                         \
    COMPUTE((kt) % 3)                                                         \
    if ((kt) < 30) {                                                          \
      asm volatile("s_waitcnt vmcnt(7)" ::: "memory");                        \
    } else {                                                                  \
      asm volatile("s_waitcnt vmcnt(0)" ::: "memory");                        \
    }                                                                         \
    if ((kt) < 31) { WRITE_A(RC, ((kt) + 1) % 3) }                            \
    asm volatile("s_waitcnt lgkmcnt(0)" ::: "memory");                        \
    __builtin_amdgcn_s_barrier();                                             \
    asm volatile("" ::: "memory");                                            \
  }

  float4 raA[4], raB[4];
  // Prologue: raA=A(0), raB=A(1); B(0)->buf0, B(1)->buf1; A(0) written to buf0.
  LOAD_A(raA, 0)
  STAGE_B(0, 0)
  LOAD_A(raB, 1)
  STAGE_B(1, 1)
  WRITE_A(raA, 0)                               // compiler waits raA's vmem
  asm volatile("s_waitcnt vmcnt(7)" ::: "memory");   // B(0) landed; raB+B(1) in flight
  asm volatile("s_waitcnt lgkmcnt(0)" ::: "memory");
  __builtin_amdgcn_s_barrier();
  asm volatile("" ::: "memory");

  for (int kt2 = 0; kt2 < 32; kt2 += 2) {
    BODY(kt2, raB, raA)                         // even kt: consume raB=A(kt+1)
    BODY(kt2 + 1, raA, raB)                     // odd kt: consume raA=A(kt+1)
  }
#undef BODY
#undef COMPUTE
#undef STAGE_B
#undef LOAD_A
#undef WRITE_A
  __syncthreads();                              // all K-loop LDS reads done before zep reuse

  // Epilogue: 4 passes of 32 rows via LDS (pitch 201 f32), fused gates,
  // hv stored in gemm2's packed-swizzled tile layout.
  const float* bp0 = bp + cby * 192;
  const int er = t >> 3, oc = t & 7;
#pragma unroll
  for (int pass = 0; pass < 4; ++pass) {
    if (wm == (pass >> 1)) {
      int mtb = (pass & 1) * 2;
#pragma unroll
      for (int mi = 0; mi < 2; ++mi)
#pragma unroll
        for (int nt = 0; nt < 6; ++nt)
#pragma unroll
          for (int r = 0; r < 4; ++r)
            zep[(mi * 16 + q * 4 + r) * 201 + wn * 96 + nt * 16 + lrow] = acc[mtb + mi][nt][r];
    }
    __syncthreads();
    {
      int ml = pass * 32 + er;                  // local row 0..127
      unsigned short v[8];
#pragma unroll
      for (int j = 0; j < 8; ++j) {
        int hl = oc * 8 + j;                    // 0..63 local h
        float zi = zep[er * 201 + hl * 3 + 0] + bp0[hl * 3 + 0];
        float zo = zep[er * 201 + hl * 3 + 1] + bp0[hl * 3 + 1];
        float zc = zep[er * 201 + hl * 3 + 2] + bp0[hl * 3 + 2];
        float it = sigmf(zi);
        float ot = sigmf(zo);
        float cc = it * tanh_(zc);
        v[j] = f2bf(ot * tanh_(cc));
      }
      int ktile = cby * 2 + (oc >> 2), qq = oc & 3;
      int idx16 = (ml << 2) + (qq ^ ((ml >> 1) & 3));
      uint4 val = make_uint4(
          (unsigned)v[0] | ((unsigned)v[1] << 16), (unsigned)v[2] | ((unsigned)v[3] << 16),
          (unsigned)v[4] | ((unsigned)v[5] << 16), (unsigned)v[6] | ((unsigned)v[7] << 16));
      *(uint4*)(hvp + (size_t)(rowt * 8 + ktile) * 4096 + idx16 * 8) = val;
    }
    __syncthreads();
  }
}

// ---------------- GEMM2: out = hv @ fco_w + fco_b (fp32 output) ----------------
__global__ __launch_bounds__(256, 4) void gemm2_k(
    const unsigned short* __restrict__ hvp, const unsigned short* __restrict__ Fp,
    const float* __restrict__ fcob, float* __restrict__ out) {
  __shared__ unsigned short sB[32768];          // 64 KB: 8 k-tiles of 128x32
  const int t = threadIdx.x;
  const int lane = t & 63, wid = t >> 6;
  const int wm = wid >> 1, wn = wid & 1;
  const int lrow = lane & 15, q = lane >> 4;
  const int mb = blockIdx.x, nb = blockIdx.y;

  const unsigned short* fpb = Fp + (size_t)nb * 32768;
#pragma unroll
  for (int i = 0; i < 16; ++i) gld16(fpb + (t + i * 256) * 8, sB + (t + i * 256) * 8);

  floatx4 acc[4][4];
#pragma unroll
  for (int i = 0; i < 4; ++i)
#pragma unroll
    for (int j = 0; j < 4; ++j) acc[i][j] = (floatx4){0.f, 0.f, 0.f, 0.f};
  __syncthreads();

#pragma unroll
  for (int kt = 0; kt < 8; ++kt) {
    const unsigned short* at_ = hvp + (size_t)(mb * 8 + kt) * 4096;
    bf16x8 af[4], bf[4];
#pragma unroll
    for (int mt = 0; mt < 4; ++mt) {
      int m = wm * 64 + mt * 16 + lrow;
      int o = (m << 2) + (q ^ ((m >> 1) & 3));
      af[mt] = *(const bf16x8*)(const void*)(at_ + o * 8);    // global, coalesced
    }
#pragma unroll
    for (int nt = 0; nt < 4; ++nt) {
      int n = wn * 64 + nt * 16 + lrow;
      int o = (n << 2) + (q ^ ((n >> 1) & 3));
      bf[nt] = *(const bf16x8*)(const void*)(sB + kt * 4096 + o * 8);
    }
#pragma unroll
    for (int mt = 0; mt < 4; ++mt)
#pragma unroll
      for (int nt = 0; nt < 4; ++nt)
        acc[mt][nt] = __builtin_amdgcn_mfma_f32_16x16x32_bf16(af[mt], bf[nt], acc[mt][nt], 0, 0, 0);
  }
#pragma unroll
  for (int nt = 0; nt < 4; ++nt) {
    int colg = nb * 128 + wn * 64 + nt * 16 + lrow;
    float bias = fcob[colg];
#pragma unroll
    for (int mt = 0; mt < 4; ++mt) {
      int rowg = mb * 128 + wm * 64 + mt * 16 + q * 4;
#pragma unroll
      for (int r = 0; r < 4; ++r)
        out[(size_t)(rowg + r) * 256 + colg] = acc[mt][nt][r] + bias;
    }
  }
}

extern "C" void kernel_launch(void* const* d_in, const int* in_sizes, int n_in,
                              void* d_out, int out_size, void* d_ws, size_t ws_size,
                              hipStream_t stream) {
  const float* x  = (const float*)d_in[0];
  const float* wr = (const float*)d_in[1];
  const float* wi = (const float*)d_in[2];
  const float* wj = (const float*)d_in[3];
  const float* wk = (const float*)d_in[4];
  const float* bx = (const float*)d_in[5];
  // d_in[6..9] = uh_* are dead (h0 == 0)
  const float* fw = (const float*)d_in[10];
  const float* fb = (const float*)d_in[11];
  char* ws = (char*)d_ws;
  unsigned short* Wp  = (unsigned short*)(ws + WS_WP);
  unsigned short* Fp  = (unsigned short*)(ws + WS_FCO);
  float*          bp  = (float*)(ws + WS_BP);
  unsigned short* hvp = (unsigned short*)(ws + WS_HVP);
  float*          out = (float*)d_out;

  hipLaunchKernelGGL(pack_k,  dim3(416),    dim3(256), 0, stream, wr, wi, wj, wk, bx, fw, Wp, Fp, bp);
  hipLaunchKernelGGL(gemm1_k, dim3(256, 4), dim3(256), 0, stream, x, Wp, bp, hvp);
  hipLaunchKernelGGL(gemm2_k, dim3(256, 2), dim3(256), 0, stream, hvp, Fp, fb, out);
}